// Round 6
// baseline (81.935 us; speedup 1.0000x reference)
//
#include <hip/hip_runtime.h>

// EnergyPool2d: N=16, C=64, H=W=128, 3x3 windows stride 1 -> Ho=Wo=126.
// +1 at first-argmax flat index, -1 at first-argmin flat index per window.
// R6 = R4 structure (grid-stride 4-wide x 2-tall tiles, 8 float4 loads,
// LDS count plane) + separable h-stat compute (max3/min3 + backward
// equality-select = exact row-major first-occurrence tie-break).

#define HH 128
#define WW 128
#define HO 126
#define WO 126
#define PLANE (HH * WW)   // 16384
#define NPLANES (16 * 64) // 1024
#define BLOCK 1024
#define CTILES 32         // ct<31 -> 4 windows wide, ct=31 -> 2
#define RTILES 63         // 2 window rows each (covers 126)
#define NTILES (CTILES * RTILES) // 2016

__global__ __launch_bounds__(BLOCK, 8)
void energy_pool2d_kernel(const float* __restrict__ x, float* __restrict__ out) {
    __shared__ int cnt[PLANE]; // 64 KB

    const int tid = threadIdx.x;
    const int plane = blockIdx.x;
    const float* __restrict__ xp = x + (size_t)plane * PLANE;

    // Zero the LDS count plane.
    int4* c4 = (int4*)cnt;
#pragma unroll
    for (int i = 0; i < PLANE / 4 / BLOCK; ++i)
        c4[tid + i * BLOCK] = make_int4(0, 0, 0, 0);
    __syncthreads();

    for (int t = tid; t < NTILES; t += BLOCK) {
        const int rt = t >> 5;       // 0..62
        const int ct = t & 31;       // 0..31
        const int wr0 = rt * 2;      // first window row (0..124)
        const int j0 = ct * 4;       // first window col
        const float* __restrict__ p = xp + wr0 * WW + j0;
        const bool cfull = (ct < CTILES - 1);

        // 4 input rows x 8 cols; right float4 skipped at the right edge
        // (edge tile uses cols 124..127 only; also keeps last row in-bounds).
        float r[4][8];
        const float4 a0 = *(const float4*)(p);
        const float4 a1 = *(const float4*)(p + WW);
        const float4 a2 = *(const float4*)(p + 2 * WW);
        const float4 a3 = *(const float4*)(p + 3 * WW);
        r[0][0] = a0.x; r[0][1] = a0.y; r[0][2] = a0.z; r[0][3] = a0.w;
        r[1][0] = a1.x; r[1][1] = a1.y; r[1][2] = a1.z; r[1][3] = a1.w;
        r[2][0] = a2.x; r[2][1] = a2.y; r[2][2] = a2.z; r[2][3] = a2.w;
        r[3][0] = a3.x; r[3][1] = a3.y; r[3][2] = a3.z; r[3][3] = a3.w;
        if (cfull) {
            const float4 b0 = *(const float4*)(p + 4);
            const float4 b1 = *(const float4*)(p + WW + 4);
            const float4 b2 = *(const float4*)(p + 2 * WW + 4);
            const float4 b3 = *(const float4*)(p + 3 * WW + 4);
            r[0][4] = b0.x; r[0][5] = b0.y; r[0][6] = b0.z; r[0][7] = b0.w;
            r[1][4] = b1.x; r[1][5] = b1.y; r[1][6] = b1.z; r[1][7] = b1.w;
            r[2][4] = b2.x; r[2][5] = b2.y; r[2][6] = b2.z; r[2][7] = b2.w;
            r[3][4] = b3.x; r[3][5] = b3.y; r[3][6] = b3.z; r[3][7] = b3.w;
        } else {
#pragma unroll
            for (int q = 0; q < 4; ++q)
                r[q][4] = r[q][5] = r[q][6] = r[q][7] = 0.f;
        }

        const int base = wr0 * WW + j0;

        // h-stats: first-occurrence 1x3 argmax/argmin per (row q, offset o).
        // Index stored as flat offset q*WW + col relative to tile base.
        float hM[4][4], hm[4][4];
        int hA[4][4], ha[4][4];
#pragma unroll
        for (int q = 0; q < 4; ++q) {
#pragma unroll
            for (int o = 0; o < 4; ++o) {
                const float v0 = r[q][o], v1 = r[q][o + 1], v2 = r[q][o + 2];
                const int f0 = q * WW + o;
                const float M = fmaxf(fmaxf(v0, v1), v2);  // v_max3_f32
                int A = f0 + 2;
                if (v1 == M) A = f0 + 1;
                if (v0 == M) A = f0;                       // first col == M
                const float m = fminf(fminf(v0, v1), v2);  // v_min3_f32
                int a = f0 + 2;
                if (v1 == m) a = f0 + 1;
                if (v0 == m) a = f0;
                hM[q][o] = M; hA[q][o] = A;
                hm[q][o] = m; ha[q][o] = a;
            }
        }

        const int nw = cfull ? 4 : 2;
#pragma unroll
        for (int o = 0; o < 4; ++o) {
            if (o < nw) {
#pragma unroll
                for (int wr = 0; wr < 2; ++wr) {
                    // Vertical first-occurrence via backward equality select.
                    const float WM =
                        fmaxf(fmaxf(hM[wr][o], hM[wr + 1][o]), hM[wr + 2][o]);
                    int wA = hA[wr + 2][o];
                    if (hM[wr + 1][o] == WM) wA = hA[wr + 1][o];
                    if (hM[wr][o] == WM) wA = hA[wr][o];
                    const float Wm =
                        fminf(fminf(hm[wr][o], hm[wr + 1][o]), hm[wr + 2][o]);
                    int wa = ha[wr + 2][o];
                    if (hm[wr + 1][o] == Wm) wa = ha[wr + 1][o];
                    if (hm[wr][o] == Wm) wa = ha[wr][o];
                    atomicAdd(&cnt[base + wA], 1);
                    atomicAdd(&cnt[base + wa], -1);
                }
            }
        }
    }
    __syncthreads();

    // Coalesced writeout: int -> float, float4 stores (whole plane overwritten).
    float4* __restrict__ o4 = (float4*)(out + (size_t)plane * PLANE);
#pragma unroll
    for (int i = 0; i < PLANE / 4 / BLOCK; ++i) {
        const int4 ci = c4[tid + i * BLOCK];
        o4[tid + i * BLOCK] =
            make_float4((float)ci.x, (float)ci.y, (float)ci.z, (float)ci.w);
    }
}

extern "C" void kernel_launch(void* const* d_in, const int* in_sizes, int n_in,
                              void* d_out, int out_size, void* d_ws, size_t ws_size,
                              hipStream_t stream) {
    const float* x = (const float*)d_in[0];
    float* out = (float*)d_out;
    energy_pool2d_kernel<<<NPLANES, BLOCK, 0, stream>>>(x, out);
}

// Round 7
// 32.088 us; speedup vs baseline: 2.5535x; 2.5535x over previous
//
#include <hip/hip_runtime.h>

// EnergyPool2d: N=16, C=64, H=W=128, 3x3 windows stride 1 -> Ho=Wo=126.
// +1 at first-argmax flat index, -1 at first-argmin flat index per window.
// R7 = R4 (grid-stride 4-wide x 2-tall tiles, 8 float4 loads, LDS count
// plane) with __launch_bounds__(1024, 4): the (1024, 8) bound capped the
// allocator at 32 VGPR and spilled the tile to scratch (R6 counters:
// WRITE_SIZE 267 MB = 4x output). Cap 128 VGPR keeps the tile in registers.

#define HH 128
#define WW 128
#define HO 126
#define WO 126
#define PLANE (HH * WW)   // 16384
#define NPLANES (16 * 64) // 1024
#define BLOCK 1024
#define CTILES 32         // ct<31 -> 4 windows, ct=31 -> 2
#define RTILES 63         // 2 window rows each (covers 126)
#define NTILES (CTILES * RTILES) // 2016

// First-occurrence argmax/argmin over a 3x3 window, row-major scan order
// (strict > / <), all offsets compile-time constants.
__device__ __forceinline__ void scan9(float w0, float w1, float w2,
                                      float w3, float w4, float w5,
                                      float w6, float w7, float w8,
                                      int base, int* __restrict__ cnt) {
    float vmax = w0, vmin = w0;
    int omax = 0, omin = 0;
#define STEP(v, off)                                      \
    do {                                                  \
        if ((v) > vmax) { vmax = (v); omax = (off); }     \
        if ((v) < vmin) { vmin = (v); omin = (off); }     \
    } while (0)
    STEP(w1, 1);
    STEP(w2, 2);
    STEP(w3, WW);
    STEP(w4, WW + 1);
    STEP(w5, WW + 2);
    STEP(w6, 2 * WW);
    STEP(w7, 2 * WW + 1);
    STEP(w8, 2 * WW + 2);
#undef STEP
    atomicAdd(&cnt[base + omax], 1);
    atomicAdd(&cnt[base + omin], -1);
}

__global__ __launch_bounds__(BLOCK, 4)
void energy_pool2d_kernel(const float* __restrict__ x, float* __restrict__ out) {
    __shared__ int cnt[PLANE]; // 64 KB

    const int tid = threadIdx.x;
    const int plane = blockIdx.x;
    const float* __restrict__ xp = x + (size_t)plane * PLANE;

    // Zero the LDS count plane.
    int4* c4 = (int4*)cnt;
#pragma unroll
    for (int i = 0; i < PLANE / 4 / BLOCK; ++i)
        c4[tid + i * BLOCK] = make_int4(0, 0, 0, 0);
    __syncthreads();

    for (int t = tid; t < NTILES; t += BLOCK) {
        const int rt = t >> 5;       // 0..62
        const int ct = t & 31;       // 0..31
        const int wr0 = rt * 2;      // first window row of tile (0..124)
        const int j0 = ct * 4;       // first window col of tile
        const float* __restrict__ p = xp + wr0 * WW + j0;

        // 4 input rows x 8 cols. Left float4 always; right float4 only for
        // ct<31 (ct=31 uses cols 124..127 only; also avoids OOB on the
        // final plane's last row).
        const float4 a0 = *(const float4*)(p);
        const float4 a1 = *(const float4*)(p + WW);
        const float4 a2 = *(const float4*)(p + 2 * WW);
        const float4 a3 = *(const float4*)(p + 3 * WW);
        float4 b0, b1, b2, b3;
        if (ct < CTILES - 1) {
            b0 = *(const float4*)(p + 4);
            b1 = *(const float4*)(p + WW + 4);
            b2 = *(const float4*)(p + 2 * WW + 4);
            b3 = *(const float4*)(p + 3 * WW + 4);
        } else {
            b0 = b1 = b2 = b3 = make_float4(0.f, 0.f, 0.f, 0.f);
        }
        const float r0[8] = {a0.x, a0.y, a0.z, a0.w, b0.x, b0.y, b0.z, b0.w};
        const float r1[8] = {a1.x, a1.y, a1.z, a1.w, b1.x, b1.y, b1.z, b1.w};
        const float r2[8] = {a2.x, a2.y, a2.z, a2.w, b2.x, b2.y, b2.z, b2.w};
        const float r3[8] = {a3.x, a3.y, a3.z, a3.w, b3.x, b3.y, b3.z, b3.w};

        const int nw = (ct < CTILES - 1) ? 4 : 2;
        const int base0 = wr0 * WW + j0;
#pragma unroll
        for (int c = 0; c < 4; ++c) {
            if (c < nw) {
                scan9(r0[c], r0[c + 1], r0[c + 2],
                      r1[c], r1[c + 1], r1[c + 2],
                      r2[c], r2[c + 1], r2[c + 2], base0 + c, cnt);
                scan9(r1[c], r1[c + 1], r1[c + 2],
                      r2[c], r2[c + 1], r2[c + 2],
                      r3[c], r3[c + 1], r3[c + 2], base0 + WW + c, cnt);
            }
        }
    }
    __syncthreads();

    // Coalesced writeout: int -> float, float4 stores (whole plane overwritten).
    float4* __restrict__ o4 = (float4*)(out + (size_t)plane * PLANE);
#pragma unroll
    for (int i = 0; i < PLANE / 4 / BLOCK; ++i) {
        const int4 ci = c4[tid + i * BLOCK];
        o4[tid + i * BLOCK] =
            make_float4((float)ci.x, (float)ci.y, (float)ci.z, (float)ci.w);
    }
}

extern "C" void kernel_launch(void* const* d_in, const int* in_sizes, int n_in,
                              void* d_out, int out_size, void* d_ws, size_t ws_size,
                              hipStream_t stream) {
    const float* x = (const float*)d_in[0];
    float* out = (float*)d_out;
    energy_pool2d_kernel<<<NPLANES, BLOCK, 0, stream>>>(x, out);
}